// Round 1
// baseline (2296.553 us; speedup 1.0000x reference)
//
#include <hip/hip_runtime.h>

typedef __bf16 bf16_t;
typedef bf16_t bf16x8 __attribute__((ext_vector_type(8)));
typedef float f32x4 __attribute__((ext_vector_type(4)));
typedef unsigned short u16;

#define P_TOTAL 98304
#define PTS_PER_BATCH 49152

__device__ __forceinline__ u16 f2bs(float f){ bf16_t b=(bf16_t)f; return __builtin_bit_cast(u16,b); }
__device__ __forceinline__ float bs2f(u16 s){ return (float)__builtin_bit_cast(bf16_t,s); }

// ---------- weight transpose: (K,N) fp32 -> (N,K) bf16 ----------
__global__ void k_wtrans15(const float* __restrict__ lz, const float* __restrict__ f0,
                           const float* __restrict__ f1, u16* __restrict__ dst){
  __shared__ float tile[32][33];
  int z = blockIdx.z;
  const float* src = (z<5) ? (lz + (size_t)z*262144)
                   : (z<10 ? (f0 + (size_t)(z-5)*262144)
                           : (f1 + (size_t)(z-10)*262144));
  u16* d = dst + (size_t)z*262144;
  int k0 = blockIdx.x*32, n0 = blockIdx.y*32;
  int t = threadIdx.x, a = t&31, r = t>>5;
  #pragma unroll
  for (int p=0;p<4;p++) tile[r+p*8][a] = src[(size_t)(k0+r+p*8)*512 + n0+a];
  __syncthreads();
  #pragma unroll
  for (int p=0;p<4;p++) d[(size_t)(n0+r+p*8)*512 + k0+a] = f2bs(tile[a][r+p*8]);
}

__global__ void k_wtrans_in(const float* __restrict__ w, u16* __restrict__ dst){
  __shared__ float tile[32][33];
  int k0 = blockIdx.x*32, n0 = blockIdx.y*32;
  int t = threadIdx.x, a = t&31, r = t>>5;
  #pragma unroll
  for (int p=0;p<4;p++){
    int k = k0+r+p*8;
    tile[r+p*8][a] = (k < 63) ? w[(size_t)k*512 + n0+a] : 0.f;
  }
  __syncthreads();
  #pragma unroll
  for (int p=0;p<4;p++) dst[(size_t)(n0+r+p*8)*64 + k0+a] = f2bs(tile[a][r+p*8]);
}

// ---------- feature transpose: (B,512,128,128) f32 -> (B,128,128,512) bf16 ----------
__global__ void k_featT(const float* __restrict__ feat, u16* __restrict__ featT){
  int x = threadIdx.x;            // 0..127
  int c8 = blockIdx.x*8;          // channel octet
  int y = blockIdx.y, b = blockIdx.z;
  float v[8];
  #pragma unroll
  for (int j=0;j<8;j++)
    v[j] = feat[(((size_t)(b*512 + c8 + j))*128 + y)*128 + x];
  bf16x8 o;
  #pragma unroll
  for (int j=0;j<8;j++) o[j] = (bf16_t)v[j];
  *(bf16x8*)(featT + (((size_t)(b*128 + y))*128 + x)*512 + c8) = o;
}

// ---------- per-point: geometry + bilinear + positional encoding ----------
__global__ void k_points(const float* __restrict__ world, const float* __restrict__ c2w,
                         const float* __restrict__ kmat, const u16* __restrict__ featT,
                         u16* __restrict__ alignedB, u16* __restrict__ encB,
                         int off, int M){
  int wid = threadIdx.x >> 6, lane = threadIdx.x & 63;
  int pl = blockIdx.x*4 + wid;
  if (pl >= M) return;
  int gp = off + pl;
  int b = gp / PTS_PER_BATCH;
  const float* wp = world + (size_t)gp*3;
  float px = wp[0], py = wp[1], pz = wp[2];
  const float* cw = c2w + b*16;
  float dx = px - cw[3], dy = py - cw[7], dz = pz - cw[11];
  // cam_i = sum_j rot[j][i] * d_j  (rot[j][i] = cw[j*4+i])
  float cx = cw[0]*dx + cw[4]*dy + cw[8]*dz;
  float cy = cw[1]*dx + cw[5]*dy + cw[9]*dz;
  float cz = cw[2]*dx + cw[6]*dy + cw[10]*dz;
  const float* km = kmat + b*9;
  float u0 = km[0]*cx + km[1]*cy + km[2]*cz;
  float v0 = km[3]*cx + km[4]*cy + km[5]*cz;
  float zz = km[6]*cx + km[7]*cy + km[8]*cz;
  if (fabsf(zz) < 1e-6f) zz = 1e-6f;
  float uu = u0/zz, vv = v0/zz;
  float xf = fminf(fmaxf(uu, 0.f), 127.f);
  float yf = fminf(fmaxf(vv, 0.f), 127.f);
  float x0f = floorf(xf), y0f = floorf(yf);
  int x0 = (int)x0f, y0 = (int)y0f;
  int x1 = min(x0+1,127), y1 = min(y0+1,127);
  float wx = xf - x0f, wy = yf - y0f;
  float w00 = (1.f-wx)*(1.f-wy), w01 = wx*(1.f-wy), w10 = (1.f-wx)*wy, w11 = wx*wy;
  size_t fb = (size_t)b*128*128*512;
  int c8 = lane*8;
  const bf16x8 t00 = *(const bf16x8*)(featT + fb + (size_t)(y0*128+x0)*512 + c8);
  const bf16x8 t01 = *(const bf16x8*)(featT + fb + (size_t)(y0*128+x1)*512 + c8);
  const bf16x8 t10 = *(const bf16x8*)(featT + fb + (size_t)(y1*128+x0)*512 + c8);
  const bf16x8 t11 = *(const bf16x8*)(featT + fb + (size_t)(y1*128+x1)*512 + c8);
  bf16x8 o;
  #pragma unroll
  for (int j=0;j<8;j++){
    float r = (float)t00[j]*w00 + (float)t01[j]*w01 + (float)t10[j]*w10 + (float)t11[j]*w11;
    o[j] = (bf16_t)r;
  }
  *(bf16x8*)(alignedB + (size_t)pl*512 + c8) = o;
  // positional encoding: [cam(3), sin(2pi*cam_i*2^f) i-major, cos(...)] pad to 64
  float cam[3] = {cx, cy, cz};
  float e;
  if (lane < 3) e = cam[lane];
  else if (lane < 33){
    int i = (lane-3)/10, f = (lane-3)%10;
    e = sinf(6.2831855f * cam[i] * (float)(1<<f));
  } else if (lane < 63){
    int i = (lane-33)/10, f = (lane-33)%10;
    e = cosf(6.2831855f * cam[i] * (float)(1<<f));
  } else e = 0.f;
  encB[(size_t)pl*64 + lane] = f2bs(e);
}

// ---------- GEMM: C = A @ B^T(stored N x K) + bias, fused epilogues ----------
// A_F32: A is fp32 and relu is applied while staging (fc0 reading h)
// ADD_H: accumulate h (residual) ; WRITE_H: write result to h (fp32)
// WRITE_ACT: write relu(result) as bf16 to act
template<int A_F32, int ADD_H, int WRITE_H, int WRITE_ACT>
__global__ __launch_bounds__(256)
void k_gemm(const void* __restrict__ Av, int lda, const u16* __restrict__ Bt, int K,
            const float* __restrict__ bias, float* __restrict__ h, u16* __restrict__ act){
  __shared__ u16 sA[2][128][40];
  __shared__ u16 sB[2][128][40];
  const int t = threadIdx.x;
  const long m0 = (long)blockIdx.y*128;
  const int n0 = blockIdx.x*128;
  f32x4 acc[4][4] = {};
  const int w = t>>6, l = t&63;
  const int wm = (w>>1)*64, wn = (w&1)*64;
  const int fm = l&15, fr = (l>>4)*8;

  auto stage = [&](int buf, int k0){
    if (A_F32){
      const float* A = (const float*)Av;
      #pragma unroll
      for (int p=0;p<4;p++){
        int row = (t>>3) + p*32, kq = t&7;
        float4 v = *(const float4*)(A + (m0+row)*(long)lda + k0 + kq*4);
        ushort4 o = make_ushort4(f2bs(fmaxf(v.x,0.f)), f2bs(fmaxf(v.y,0.f)),
                                 f2bs(fmaxf(v.z,0.f)), f2bs(fmaxf(v.w,0.f)));
        *(ushort4*)&sA[buf][row][kq*4] = o;
      }
    } else {
      const u16* A = (const u16*)Av;
      #pragma unroll
      for (int p=0;p<2;p++){
        int row = (t>>2) + p*64, kq = t&3;
        *(uint4*)&sA[buf][row][kq*8] = *(const uint4*)(A + (m0+row)*(long)lda + k0 + kq*8);
      }
    }
    #pragma unroll
    for (int p=0;p<2;p++){
      int row = (t>>2) + p*64, kq = t&3;
      *(uint4*)&sB[buf][row][kq*8] = *(const uint4*)(Bt + (long)(n0+row)*K + k0 + kq*8);
    }
  };

  stage(0, 0);
  __syncthreads();
  const int nk = K >> 5;
  for (int kt = 0; kt < nk; ++kt){
    int cur = kt & 1;
    if (kt+1 < nk) stage(cur^1, (kt+1)<<5);
    bf16x8 a[4], b[4];
    #pragma unroll
    for (int i=0;i<4;i++){
      a[i] = *(const bf16x8*)&sA[cur][wm + i*16 + fm][fr];
      b[i] = *(const bf16x8*)&sB[cur][wn + i*16 + fm][fr];
    }
    #pragma unroll
    for (int mi=0;mi<4;mi++)
      #pragma unroll
      for (int ni=0;ni<4;ni++)
        acc[mi][ni] = __builtin_amdgcn_mfma_f32_16x16x32_bf16(a[mi], b[ni], acc[mi][ni], 0,0,0);
    __syncthreads();
  }
  // epilogue: C/D layout col=lane&15, row=(lane>>4)*4+reg
  const int col = l&15, rq = (l>>4)*4;
  #pragma unroll
  for (int mi=0;mi<4;mi++){
    #pragma unroll
    for (int ni=0;ni<4;ni++){
      int gn = n0 + wn + ni*16 + col;
      float bs = bias[gn];
      #pragma unroll
      for (int r=0;r<4;r++){
        long gm = m0 + wm + mi*16 + rq + r;
        float v = acc[mi][ni][r] + bs;
        size_t idx = (size_t)gm*512 + gn;
        if (ADD_H) v += h[idx];
        if (WRITE_H) h[idx] = v;
        if (WRITE_ACT) act[idx] = f2bs(fmaxf(v, 0.f));
      }
    }
  }
}

// ---------- final: sigma = exp(relu(h) . w_out + b_out) ----------
__global__ void k_sigma(const float* __restrict__ h, const float* __restrict__ wout,
                        const float* __restrict__ bout, float* __restrict__ out, int M){
  int wid = threadIdx.x>>6, lane = threadIdx.x&63;
  int pl = blockIdx.x*4 + wid;
  if (pl >= M) return;
  const float* hp = h + (size_t)pl*512 + lane*8;
  float4 a = *(const float4*)hp, b = *(const float4*)(hp+4);
  const float* wp = wout + lane*8;
  float4 wa = *(const float4*)wp, wb = *(const float4*)(wp+4);
  float acc = fmaxf(a.x,0.f)*wa.x + fmaxf(a.y,0.f)*wa.y + fmaxf(a.z,0.f)*wa.z + fmaxf(a.w,0.f)*wa.w
            + fmaxf(b.x,0.f)*wb.x + fmaxf(b.y,0.f)*wb.y + fmaxf(b.z,0.f)*wb.z + fmaxf(b.w,0.f)*wb.w;
  #pragma unroll
  for (int o2=32; o2; o2>>=1) acc += __shfl_down(acc, o2);
  if (lane == 0) out[pl] = expf(acc + bout[0]);
}

extern "C" void kernel_launch(void* const* d_in, const int* in_sizes, int n_in,
                              void* d_out, int out_size, void* d_ws, size_t ws_size,
                              hipStream_t stream) {
  const float* world = (const float*)d_in[0];
  const float* c2w   = (const float*)d_in[1];
  const float* kmat  = (const float*)d_in[2];
  const float* feat  = (const float*)d_in[3];
  const float* w_in  = (const float*)d_in[4];
  const float* b_in  = (const float*)d_in[5];
  const float* w_z   = (const float*)d_in[6];
  const float* b_z   = (const float*)d_in[7];
  const float* w_f0  = (const float*)d_in[8];
  const float* b_f0  = (const float*)d_in[9];
  const float* w_f1  = (const float*)d_in[10];
  const float* b_f1  = (const float*)d_in[11];
  const float* w_out = (const float*)d_in[12];
  const float* b_out = (const float*)d_in[13];
  float* out = (float*)d_out;
  char* ws = (char*)d_ws;

  size_t off = 0;
  u16* wts   = (u16*)(ws + off); off += (size_t)15*262144*2;       // 15x (512x512) bf16 N-major
  u16* wtin  = (u16*)(ws + off); off += (size_t)512*64*2;          // (512x64) bf16
  u16* featT = (u16*)(ws + off); off += (size_t)2*128*128*512*2;   // transposed features
  size_t fixed = off;

  const size_t per_pt = 1024 /*aligned*/ + 2048 /*h f32*/ + 1024 /*act*/ + 128 /*enc*/;
  long avail = (long)ws_size - (long)fixed;
  long cm = avail > 0 ? avail / (long)per_pt : 0;
  int chunkM = (int)(cm/128)*128;
  if (chunkM > P_TOTAL) chunkM = P_TOTAL;
  if (chunkM < 128) chunkM = 128;

  u16*   alignedB = (u16*)(ws + fixed);
  float* hbuf     = (float*)(ws + fixed + (size_t)chunkM*1024);
  u16*   actb     = (u16*)(ws + fixed + (size_t)chunkM*(1024+2048));
  u16*   encB     = (u16*)(ws + fixed + (size_t)chunkM*(1024+2048+1024));

  // one-time per call: weights + feature transpose
  k_wtrans15<<<dim3(16,16,15), 256, 0, stream>>>(w_z, w_f0, w_f1, wts);
  k_wtrans_in<<<dim3(2,16,1), 256, 0, stream>>>(w_in, wtin);
  k_featT<<<dim3(64,128,2), 128, 0, stream>>>(feat, featT);

  for (int po = 0; po < P_TOTAL; po += chunkM){
    int M = P_TOTAL - po; if (M > chunkM) M = chunkM;
    k_points<<<dim3(M/4), 256, 0, stream>>>(world, c2w, kmat, featT, alignedB, encB, po, M);
    dim3 gg(4, M/128);
    // h = enc @ W_in + b_in
    k_gemm<0,0,1,0><<<gg, 256, 0, stream>>>((const void*)encB, 64, wtin, 64, b_in, hbuf, (u16*)nullptr);
    for (int i=0;i<5;i++){
      // h += aligned @ Wz_i + bz_i
      k_gemm<0,1,1,0><<<gg, 256, 0, stream>>>((const void*)alignedB, 512,
          wts + (size_t)i*262144, 512, b_z + i*512, hbuf, (u16*)nullptr);
      // act = relu( relu(h) @ W0_i + b0_i )
      k_gemm<1,0,0,1><<<gg, 256, 0, stream>>>((const void*)hbuf, 512,
          wts + (size_t)(5+i)*262144, 512, b_f0 + i*512, hbuf, actb);
      // h += act @ W1_i + b1_i
      k_gemm<0,1,1,0><<<gg, 256, 0, stream>>>((const void*)actb, 512,
          wts + (size_t)(10+i)*262144, 512, b_f1 + i*512, hbuf, (u16*)nullptr);
    }
    k_sigma<<<dim3(M/4), 256, 0, stream>>>(hbuf, w_out, b_out, out + po, M);
  }
}